// Round 2
// baseline (836.867 us; speedup 1.0000x reference)
//
#include <hip/hip_runtime.h>
#include <cstddef>
#include <cstdint>

// LocalAttention: x[4,4096,512] -> qkv -> 5x5 neighborhood attention (8 heads, d=64)
// -> out projection.
// Round 2: same 3-kernel fp32-compute structure as round 1, but Q/K/V/AO are
// stored in bf16 (raw ushort) => workspace 64 MB (was 128 MB — hedge against a
// possible ws_size overflow that may have killed the container) and half the
// attention-stage memory traffic.
//   1) gemm_nt<float,0>:  qkv = x @ w_qkv^T  -> bf16 Q/K/V head-major [b][h][n][64]
//   2) attn_local: wave-per-(b,h,pixel), 25-neighbor softmax attn (zero-pad => logit 0)
//   3) gemm_nt<ushort,1>: out = AO @ w_out^T + b_out (fp32 out)

namespace {

constexpr int kHeads = 8;
constexpr int kHd = 64;
constexpr int kDim = 512;
constexpr int kB = 4;
constexpr int kN = 64 * 64;       // 4096 pixels
constexpr float kScale = 0.125f;  // 64^-0.5

__device__ inline float b2f(unsigned short u) {
  return __uint_as_float((unsigned)u << 16);
}
__device__ inline unsigned short f2b(float x) {
  unsigned u = __float_as_uint(x);  // RNE; NaN not expected in this data
  return (unsigned short)((u + 0x7fffu + ((u >> 16) & 1u)) >> 16);
}

__device__ inline float4 loadA4(const float* p) { return *(const float4*)p; }
__device__ inline float4 loadA4(const unsigned short* p) {
  ushort4 u = *(const ushort4*)p;
  return make_float4(b2f(u.x), b2f(u.y), b2f(u.z), b2f(u.w));
}

// ---------------- GEMM: C = A (M x 512) * W^T (W is Nout x 512, row-major) ----
// 128x128 block tile, BK=16, 256 threads, 8x8 per thread, fp32 accumulate.
// EPI 0: scatter bf16 into Q/K/V head-major.  EPI 1: add bias, fp32 row-major.
template <typename TA, int EPI>
__global__ __launch_bounds__(256) void gemm_nt(
    const TA* __restrict__ A, const float* __restrict__ W,
    const float* __restrict__ bias, void* __restrict__ C0,
    void* __restrict__ C1, void* __restrict__ C2) {
  __shared__ __align__(16) float As[16][132];
  __shared__ __align__(16) float Bs[16][132];

  const int tid = threadIdx.x;
  const int tx = tid & 15;  // output col group
  const int ty = tid >> 4;  // output row group
  const int m0 = blockIdx.y * 128;
  const int n0 = blockIdx.x * 128;

  const int lr = tid >> 2;       // 0..63: row within half-tile for staging
  const int lc = (tid & 3) * 4;  // k offset 0,4,8,12

  float acc[8][8];
#pragma unroll
  for (int i = 0; i < 8; ++i)
#pragma unroll
    for (int j = 0; j < 8; ++j) acc[i][j] = 0.f;

  for (int k0 = 0; k0 < 512; k0 += 16) {
#pragma unroll
    for (int it = 0; it < 2; ++it) {
      const int row = lr + it * 64;
      const float4 a4 = loadA4(A + (size_t)(m0 + row) * 512 + k0 + lc);
      As[lc + 0][row] = a4.x;
      As[lc + 1][row] = a4.y;
      As[lc + 2][row] = a4.z;
      As[lc + 3][row] = a4.w;
      const float4 b4 =
          *(const float4*)(W + (size_t)(n0 + row) * 512 + k0 + lc);
      Bs[lc + 0][row] = b4.x;
      Bs[lc + 1][row] = b4.y;
      Bs[lc + 2][row] = b4.z;
      Bs[lc + 3][row] = b4.w;
    }
    __syncthreads();
#pragma unroll
    for (int kk = 0; kk < 16; ++kk) {
      float a[8], b[8];
      *(float4*)&a[0] = *(const float4*)&As[kk][ty * 8];
      *(float4*)&a[4] = *(const float4*)&As[kk][ty * 8 + 4];
      *(float4*)&b[0] = *(const float4*)&Bs[kk][tx * 8];
      *(float4*)&b[4] = *(const float4*)&Bs[kk][tx * 8 + 4];
#pragma unroll
      for (int i = 0; i < 8; ++i)
#pragma unroll
        for (int j = 0; j < 8; ++j) acc[i][j] = fmaf(a[i], b[j], acc[i][j]);
    }
    __syncthreads();
  }

  if (EPI == 0) {
    // f = n0 + tx*8 + j; which=f>>9 (q/k/v), head=(f>>6)&7, d=f&63.
    // n0 is 128-aligned so `which` is block-uniform and a thread's 8 cols stay
    // inside one head: pack 8 bf16 -> one 16B store.
    unsigned short* bufs[3] = {(unsigned short*)C0, (unsigned short*)C1,
                               (unsigned short*)C2};
    const int fbase = n0 + tx * 8;
    unsigned short* dst = bufs[fbase >> 9];
    const int head = (fbase >> 6) & 7;
    const int d = fbase & 63;
#pragma unroll
    for (int i = 0; i < 8; ++i) {
      const int m = m0 + ty * 8 + i;
      const int b = m >> 12;  // / 4096
      const int p = m & 4095;
      unsigned short* o =
          dst + (((size_t)(b * kHeads + head) * kN + p) * kHd + d);
      uint4 pk;
      pk.x = ((unsigned)f2b(acc[i][1]) << 16) | f2b(acc[i][0]);
      pk.y = ((unsigned)f2b(acc[i][3]) << 16) | f2b(acc[i][2]);
      pk.z = ((unsigned)f2b(acc[i][5]) << 16) | f2b(acc[i][4]);
      pk.w = ((unsigned)f2b(acc[i][7]) << 16) | f2b(acc[i][6]);
      *(uint4*)o = pk;
    }
  } else {
    float* out = (float*)C0;
    const int fbase = n0 + tx * 8;
    float bv[8];
#pragma unroll
    for (int j = 0; j < 8; ++j) bv[j] = bias[fbase + j];
#pragma unroll
    for (int i = 0; i < 8; ++i) {
      const int m = m0 + ty * 8 + i;
      float* o = out + (size_t)m * 512 + fbase;
      *(float4*)(o) = make_float4(acc[i][0] + bv[0], acc[i][1] + bv[1],
                                  acc[i][2] + bv[2], acc[i][3] + bv[3]);
      *(float4*)(o + 4) = make_float4(acc[i][4] + bv[4], acc[i][5] + bv[5],
                                      acc[i][6] + bv[6], acc[i][7] + bv[7]);
    }
  }
}

// ---------------- local attention: one wave per (b, head, pixel) -------------
// lane <-> head_dim element. 25 dots via wave butterfly reduce; zero-padded
// OOB neighbors contribute logit 0 (matching the reference's zero-pad conv).
__global__ __launch_bounds__(256) void attn_local(
    const unsigned short* __restrict__ Q, const unsigned short* __restrict__ K,
    const unsigned short* __restrict__ V, unsigned short* __restrict__ AO) {
  const int lane = threadIdx.x & 63;
  const int wid = blockIdx.x * 4 + (threadIdx.x >> 6);
  const int b = wid >> 15;  // / (8*4096)
  const int hd = (wid >> 12) & 7;
  const int p = wid & 4095;
  const int py = p >> 6;
  const int px = p & 63;

  const size_t base = (size_t)(b * kHeads + hd) * kN;
  const float qv = b2f(Q[(base + p) * kHd + lane]);

  float dots[25];
#pragma unroll
  for (int f = 0; f < 25; ++f) {
    const int ny = py + f / 5 - 2;
    const int nx = px + f % 5 - 2;
    const bool valid = ((unsigned)ny < 64u) && ((unsigned)nx < 64u);
    float d = 0.f;
    if (valid) {
      const float kv = b2f(K[(base + (ny << 6) + nx) * kHd + lane]);
      d = qv * kv;
    }
#pragma unroll
    for (int off = 32; off > 0; off >>= 1) d += __shfl_xor(d, off, 64);
    dots[f] = d * kScale;
  }

  float mx = dots[0];
#pragma unroll
  for (int f = 1; f < 25; ++f) mx = fmaxf(mx, dots[f]);
  float sum = 0.f;
#pragma unroll
  for (int f = 0; f < 25; ++f) {
    dots[f] = __expf(dots[f] - mx);
    sum += dots[f];
  }
  const float inv = 1.f / sum;

  float o = 0.f;
#pragma unroll
  for (int f = 0; f < 25; ++f) {
    const int ny = py + f / 5 - 2;
    const int nx = px + f % 5 - 2;
    const bool valid = ((unsigned)ny < 64u) && ((unsigned)nx < 64u);
    if (valid) {
      const float vv = b2f(V[(base + (ny << 6) + nx) * kHd + lane]);
      o = fmaf(dots[f], vv, o);
    }
  }
  o *= inv;
  // attn_out layout [b][n][head*64+d] for the out-projection GEMM
  AO[((size_t)(b * kN + p)) * kDim + hd * kHd + lane] = f2b(o);
}

}  // namespace

extern "C" void kernel_launch(void* const* d_in, const int* in_sizes, int n_in,
                              void* d_out, int out_size, void* d_ws,
                              size_t ws_size, hipStream_t stream) {
  (void)in_sizes; (void)n_in; (void)out_size; (void)ws_size;
  const float* x = (const float*)d_in[0];      // [4,4096,512]
  const float* w_qkv = (const float*)d_in[1];  // [1536,512]
  const float* w_out = (const float*)d_in[2];  // [512,512]
  const float* b_out = (const float*)d_in[3];  // [512]
  float* out = (float*)d_out;                  // [4,4096,512]

  const size_t per = (size_t)kB * kHeads * kN * kHd;  // 8,388,608 elems (bf16)
  unsigned short* Q = (unsigned short*)d_ws;
  unsigned short* Kb = Q + per;
  unsigned short* Vb = Kb + per;
  unsigned short* AO = Vb + per;  // [16384][512] bf16
  // total ws use: 4 * 8,388,608 * 2 B = 64 MB

  dim3 blk(256);
  // qkv projection + head-major bf16 scatter: grid (1536/128, 16384/128)
  gemm_nt<float, 0><<<dim3(12, 128), blk, 0, stream>>>(x, w_qkv, nullptr, Q,
                                                       Kb, Vb);
  // attention: 4*8*4096 waves / 4 waves per block
  attn_local<<<dim3(kB * kHeads * kN / 4), blk, 0, stream>>>(Q, Kb, Vb, AO);
  // out projection: grid (512/128, 16384/128)
  gemm_nt<unsigned short, 1><<<dim3(4, 128), blk, 0, stream>>>(
      AO, w_out, b_out, out, nullptr, nullptr);
}

// Round 3
// 199.932 us; speedup vs baseline: 4.1858x; 4.1858x over previous
//
#include <hip/hip_runtime.h>
#include <cstddef>
#include <cstdint>

// LocalAttention on MI355X, round 3: MFMA bf16 GEMMs + per-thread-pixel local
// attention with LDS halo staging.
//   k0 cvt_w:      w_qkv, w_out fp32 -> bf16
//   k1 gemm<0>:    qkv = x @ w_qkv^T (MFMA 16x16x32 bf16, x cvt in staging)
//                  -> bf16 Q/K/V head-major [bh][p][64]
//   k2 attn_qk:    16x16 pixel tile/block, 20x20 K-halo in LDS, per-thread
//                  25-dot softmax -> attn weights bf16 [bh][p][32(25 used)]
//   k3 attn_pv:    V-halo in LDS, out = sum_f attn*V -> AO bf16 [b][p][512]
//                  (AO aliases Q: dead after k2)
//   k4 gemm<1>:    out = AO @ w_out^T + b_out (fp32)
// ws total: 60.8 MB (< 64 MB proven safe in round 2)

namespace {

typedef short s16x8 __attribute__((ext_vector_type(8)));
typedef unsigned short u16x8 __attribute__((ext_vector_type(8)));
typedef float f32x4 __attribute__((ext_vector_type(4)));

constexpr int kHeads = 8;
constexpr int kHd = 64;
constexpr int kDim = 512;
constexpr int kN = 4096;          // pixels per (b) image
constexpr float kScale = 0.125f;  // 64^-0.5

__device__ inline float b2f(unsigned short u) {
  return __uint_as_float((unsigned)u << 16);
}
__device__ inline unsigned short f2b(float x) {
  unsigned u = __float_as_uint(x);  // RNE
  return (unsigned short)((u + 0x7fffu + ((u >> 16) & 1u)) >> 16);
}

// ---------------- weight fp32 -> bf16 ----------------------------------------
__global__ __launch_bounds__(256) void cvt_w(
    const float* __restrict__ w1, const float* __restrict__ w2,
    unsigned short* __restrict__ o1, unsigned short* __restrict__ o2) {
  const int gid = blockIdx.x * 256 + threadIdx.x;
  const int gs = gridDim.x * 256;
  for (int i = gid; i < 786432 / 4; i += gs) {
    float4 v = ((const float4*)w1)[i];
    ushort4 o;
    o.x = f2b(v.x); o.y = f2b(v.y); o.z = f2b(v.z); o.w = f2b(v.w);
    ((ushort4*)o1)[i] = o;
  }
  for (int i = gid; i < 262144 / 4; i += gs) {
    float4 v = ((const float4*)w2)[i];
    ushort4 o;
    o.x = f2b(v.x); o.y = f2b(v.y); o.z = f2b(v.z); o.w = f2b(v.w);
    ((ushort4*)o2)[i] = o;
  }
}

// ---------------- MFMA GEMM: C = A (M x 512) * W^T ---------------------------
// W is bf16 [N][512] (rows k-contiguous). 128x128 tile, BK=32, 256 thr=4 waves,
// wave computes 64x64 via 4x4 grid of 16x16x32 MFMAs.
// EPI 0: A fp32 (cvt in staging), scatter bf16 Q/K/V head-major.
// EPI 1: A bf16, add bias, fp32 row-major out.
template <int EPI, typename TA>
__global__ __launch_bounds__(256) void gemm_mfma(
    const TA* __restrict__ A, const unsigned short* __restrict__ W,
    const float* __restrict__ bias, unsigned short* __restrict__ Qb,
    unsigned short* __restrict__ Kb, unsigned short* __restrict__ Vb,
    float* __restrict__ out) {
  __shared__ unsigned short As[128 * 40];  // stride 40 elems = 80 B (16B-aligned)
  __shared__ unsigned short Bs[128 * 40];

  const int tid = threadIdx.x;
  const int lane = tid & 63;
  const int wv = tid >> 6;
  const int wm = wv & 1;   // row half
  const int wn = wv >> 1;  // col half
  const int m0 = blockIdx.y * 128;
  const int n0 = blockIdx.x * 128;

  f32x4 acc[4][4];
#pragma unroll
  for (int i = 0; i < 4; ++i)
#pragma unroll
    for (int j = 0; j < 4; ++j) acc[i][j] = f32x4{0.f, 0.f, 0.f, 0.f};

  for (int k0 = 0; k0 < 512; k0 += 32) {
    if constexpr (sizeof(TA) == 4) {
      // fp32 A: 128 rows x 8 float4-segments
#pragma unroll
      for (int it = 0; it < 4; ++it) {
        const int idx = tid + it * 256;
        const int row = idx >> 3, seg = idx & 7;
        const float4 v =
            *(const float4*)((const float*)A + (size_t)(m0 + row) * 512 + k0 + seg * 4);
        ushort4 o;
        o.x = f2b(v.x); o.y = f2b(v.y); o.z = f2b(v.z); o.w = f2b(v.w);
        *(ushort4*)&As[row * 40 + seg * 4] = o;
      }
    } else {
      // bf16 A: 128 rows x 4 ushort8-segments
#pragma unroll
      for (int it = 0; it < 2; ++it) {
        const int idx = tid + it * 256;
        const int row = idx >> 2, seg = idx & 3;
        *(u16x8*)&As[row * 40 + seg * 8] = *(const u16x8*)(
            (const unsigned short*)A + (size_t)(m0 + row) * 512 + k0 + seg * 8);
      }
    }
#pragma unroll
    for (int it = 0; it < 2; ++it) {
      const int idx = tid + it * 256;
      const int row = idx >> 2, seg = idx & 3;
      *(u16x8*)&Bs[row * 40 + seg * 8] =
          *(const u16x8*)(W + (size_t)(n0 + row) * 512 + k0 + seg * 8);
    }
    __syncthreads();

    s16x8 af[4], bf[4];
#pragma unroll
    for (int i = 0; i < 4; ++i) {
      af[i] = *(const s16x8*)&As[(wm * 64 + i * 16 + (lane & 15)) * 40 +
                                 (lane >> 4) * 8];
      bf[i] = *(const s16x8*)&Bs[(wn * 64 + i * 16 + (lane & 15)) * 40 +
                                 (lane >> 4) * 8];
    }
#pragma unroll
    for (int i = 0; i < 4; ++i)
#pragma unroll
      for (int j = 0; j < 4; ++j)
        acc[i][j] =
            __builtin_amdgcn_mfma_f32_16x16x32_bf16(af[i], bf[j], acc[i][j], 0, 0, 0);
    __syncthreads();
  }

  if (EPI == 0) {
    // col n = cn + ni*16 + (lane&15); cn 64-aligned => head & q/k/v uniform/wave
    const int cn = n0 + wn * 64;
    unsigned short* dst = (cn < 512) ? Qb : (cn < 1024 ? Kb : Vb);
    const int head = (cn >> 6) & 7;
    const int colb = lane & 15;
#pragma unroll
    for (int mi = 0; mi < 4; ++mi) {
#pragma unroll
      for (int r = 0; r < 4; ++r) {
        const int m = m0 + wm * 64 + mi * 16 + (lane >> 4) * 4 + r;
        const int b = m >> 12;
        const int p = m & 4095;
        unsigned short* o =
            dst + ((size_t)(b * kHeads + head) * kN + p) * kHd + colb;
#pragma unroll
        for (int ni = 0; ni < 4; ++ni) o[ni * 16] = f2b(acc[mi][ni][r]);
      }
    }
  } else {
    float bvr[4];
#pragma unroll
    for (int ni = 0; ni < 4; ++ni)
      bvr[ni] = bias[n0 + wn * 64 + ni * 16 + (lane & 15)];
#pragma unroll
    for (int mi = 0; mi < 4; ++mi) {
#pragma unroll
      for (int r = 0; r < 4; ++r) {
        const int m = m0 + wm * 64 + mi * 16 + (lane >> 4) * 4 + r;
        float* o = out + (size_t)m * 512 + n0 + wn * 64 + (lane & 15);
#pragma unroll
        for (int ni = 0; ni < 4; ++ni) o[ni * 16] = acc[mi][ni][r] + bvr[ni];
      }
    }
  }
}

// ---------------- attention QK + softmax -------------------------------------
// Block: 16x16 pixel tile of one (b,h). LDS: 20x20 K-halo, stride 72 (16B ok).
// Thread = one pixel: 25 dots as dense FMA vs LDS rows; OOB rows zero => logit
// 0 participates in softmax (matches zero-pad reference).
__global__ __launch_bounds__(256) void attn_qk(
    const unsigned short* __restrict__ Q, const unsigned short* __restrict__ K,
    unsigned short* __restrict__ attnW) {
  __shared__ unsigned short Kh[400 * 72];  // 57.6 KB
  const int tid = threadIdx.x;
  const int bh = blockIdx.y;
  const int tile = blockIdx.x;
  const int ty0 = (tile >> 2) * 16, tx0 = (tile & 3) * 16;
  const size_t base = (size_t)bh * kN;

  for (int i = tid; i < 3200; i += 256) {
    const int r = i >> 3, c = i & 7;
    const int gy = ty0 - 2 + r / 20;
    const int gx = tx0 - 2 + r % 20;
    u16x8 v = {};
    if ((unsigned)gy < 64u && (unsigned)gx < 64u)
      v = *(const u16x8*)(K + (base + gy * 64 + gx) * 64 + c * 8);
    *(u16x8*)&Kh[r * 72 + c * 8] = v;
  }
  __syncthreads();

  const int pyl = tid >> 4, pxl = tid & 15;
  const int p = (ty0 + pyl) * 64 + tx0 + pxl;

  float q[64];
  {
    const unsigned short* qp = Q + (base + p) * 64;
#pragma unroll
    for (int c = 0; c < 8; ++c) {
      const u16x8 v = *(const u16x8*)(qp + c * 8);
#pragma unroll
      for (int j = 0; j < 8; ++j) q[c * 8 + j] = b2f(v[j]);
    }
  }

  float dots[25];
  float mx = -1e30f;
#pragma unroll
  for (int fy = 0; fy < 5; ++fy) {
#pragma unroll
    for (int fx = 0; fx < 5; ++fx) {
      const unsigned short* kr = &Kh[((pyl + fy) * 20 + pxl + fx) * 72];
      float d = 0.f;
#pragma unroll
      for (int c = 0; c < 8; ++c) {
        const u16x8 kv = *(const u16x8*)(kr + c * 8);
#pragma unroll
        for (int j = 0; j < 8; ++j) d = fmaf(q[c * 8 + j], b2f(kv[j]), d);
      }
      d *= kScale;
      dots[fy * 5 + fx] = d;
      mx = fmaxf(mx, d);
    }
  }
  float sum = 0.f;
#pragma unroll
  for (int f = 0; f < 25; ++f) {
    dots[f] = __expf(dots[f] - mx);
    sum += dots[f];
  }
  const float inv = 1.f / sum;
  unsigned short* ap = attnW + (base + p) * 32;
#pragma unroll
  for (int f = 0; f < 25; ++f) ap[f] = f2b(dots[f] * inv);
}

// ---------------- attention PV ----------------------------------------------
__global__ __launch_bounds__(256) void attn_pv(
    const unsigned short* __restrict__ V, const unsigned short* __restrict__ attnW,
    unsigned short* __restrict__ AO) {
  __shared__ unsigned short Vh[400 * 72];
  const int tid = threadIdx.x;
  const int bh = blockIdx.y;
  const int tile = blockIdx.x;
  const int ty0 = (tile >> 2) * 16, tx0 = (tile & 3) * 16;
  const size_t base = (size_t)bh * kN;

  for (int i = tid; i < 3200; i += 256) {
    const int r = i >> 3, c = i & 7;
    const int gy = ty0 - 2 + r / 20;
    const int gx = tx0 - 2 + r % 20;
    u16x8 v = {};
    if ((unsigned)gy < 64u && (unsigned)gx < 64u)
      v = *(const u16x8*)(V + (base + gy * 64 + gx) * 64 + c * 8);
    *(u16x8*)&Vh[r * 72 + c * 8] = v;
  }
  __syncthreads();

  const int pyl = tid >> 4, pxl = tid & 15;
  const int p = (ty0 + pyl) * 64 + tx0 + pxl;

  float w[25];
  {
    const unsigned short* ap = attnW + (base + p) * 32;
#pragma unroll
    for (int f = 0; f < 25; ++f) w[f] = b2f(ap[f]);
  }

  float o[64];
#pragma unroll
  for (int j = 0; j < 64; ++j) o[j] = 0.f;

#pragma unroll
  for (int fy = 0; fy < 5; ++fy) {
#pragma unroll
    for (int fx = 0; fx < 5; ++fx) {
      const unsigned short* vr = &Vh[((pyl + fy) * 20 + pxl + fx) * 72];
      const float wf = w[fy * 5 + fx];
#pragma unroll
      for (int c = 0; c < 8; ++c) {
        const u16x8 vv = *(const u16x8*)(vr + c * 8);
#pragma unroll
        for (int j = 0; j < 8; ++j)
          o[c * 8 + j] = fmaf(wf, b2f(vv[j]), o[c * 8 + j]);
      }
    }
  }

  const int b = bh >> 3, h = bh & 7;
  unsigned short* op = AO + ((size_t)(b * kN + p)) * kDim + h * kHd;
#pragma unroll
  for (int c = 0; c < 8; ++c) {
    u16x8 pk;
#pragma unroll
    for (int j = 0; j < 8; ++j) pk[j] = f2b(o[c * 8 + j]);
    *(u16x8*)(op + c * 8) = pk;
  }
}

}  // namespace

extern "C" void kernel_launch(void* const* d_in, const int* in_sizes, int n_in,
                              void* d_out, int out_size, void* d_ws,
                              size_t ws_size, hipStream_t stream) {
  (void)in_sizes; (void)n_in; (void)out_size; (void)ws_size;
  const float* x = (const float*)d_in[0];      // [4,4096,512]
  const float* w_qkv = (const float*)d_in[1];  // [1536,512]
  const float* w_out = (const float*)d_in[2];  // [512,512]
  const float* b_out = (const float*)d_in[3];  // [512]
  float* out = (float*)d_out;                  // [4,4096,512] fp32

  unsigned short* ws = (unsigned short*)d_ws;
  unsigned short* wqkvb = ws;                  // 786,432
  unsigned short* woutb = ws + 786432;         // 262,144
  unsigned short* Qb = ws + 1048576;           // 8,388,608 each
  unsigned short* Kb = Qb + 8388608;
  unsigned short* Vb = Kb + 8388608;
  unsigned short* attnW = Vb + 8388608;        // 131072*32 = 4,194,304
  unsigned short* AO = Qb;                     // alias: Q dead after attn_qk
  // total: 30,408,704 ushort = 60.8 MB

  cvt_w<<<512, 256, 0, stream>>>(w_qkv, w_out, wqkvb, woutb);
  gemm_mfma<0, float><<<dim3(12, 128), 256, 0, stream>>>(
      x, wqkvb, nullptr, Qb, Kb, Vb, nullptr);
  attn_qk<<<dim3(16, 32), 256, 0, stream>>>(Qb, Kb, attnW);
  attn_pv<<<dim3(16, 32), 256, 0, stream>>>(Vb, attnW, AO);
  gemm_mfma<1, unsigned short><<<dim3(4, 128), 256, 0, stream>>>(
      AO, woutb, b_out, nullptr, nullptr, nullptr, out);
}

// Round 4
// 193.906 us; speedup vs baseline: 4.3158x; 1.0311x over previous
//
#include <hip/hip_runtime.h>
#include <cstddef>
#include <cstdint>

// LocalAttention MI355X round 4.
//   cvt_w:     weights fp32->bf16
//   cvt_x:     x fp32->bf16, one 8192-row half at a time (xbh reused as attnW)
//   gemm_qkv:  xbh @ w_qkv^T via MFMA 16x16x32, global_load_lds(16B) staging,
//              XCD-swizzled grid; scatters bf16 Q/K/V head-major  (x2 halves)
//   attn_qk:   16x16 pixel tile, 20x20 K-halo LDS, per-thread 25-dot softmax
//   attn_pv:   V-halo, weighted sum -> AO (aliases Q)
//   gemm_out:  AO @ w_out^T + b_out -> fp32 out
// ws: 60.8 MB layout identical to round 3 (proven safe).

namespace {

typedef short s16x8 __attribute__((ext_vector_type(8)));
typedef unsigned short u16x8 __attribute__((ext_vector_type(8)));
typedef float f32x4 __attribute__((ext_vector_type(4)));

constexpr int kHeads = 8;
constexpr int kN = 4096;          // pixels per image
constexpr float kScale = 0.125f;  // 64^-0.5

__device__ inline float b2f(unsigned short u) {
  return __uint_as_float((unsigned)u << 16);
}
__device__ inline unsigned short f2b(float x) {
  unsigned u = __float_as_uint(x);  // RNE
  return (unsigned short)((u + 0x7fffu + ((u >> 16) & 1u)) >> 16);
}

// async global->LDS, 16 B per lane; LDS dest = wave-uniform base + lane*16
__device__ __forceinline__ void g2l16(const unsigned short* g,
                                      unsigned short* l) {
  __builtin_amdgcn_global_load_lds(
      (const __attribute__((address_space(1))) void*)g,
      (__attribute__((address_space(3))) void*)l, 16, 0, 0);
}

// ---------------- converts ---------------------------------------------------
__global__ __launch_bounds__(256) void cvt_w(
    const float* __restrict__ w1, const float* __restrict__ w2,
    unsigned short* __restrict__ o1, unsigned short* __restrict__ o2) {
  const int gid = blockIdx.x * 256 + threadIdx.x;
  const int gs = gridDim.x * 256;
  for (int i = gid; i < 786432 / 4; i += gs) {
    float4 v = ((const float4*)w1)[i];
    ushort4 o;
    o.x = f2b(v.x); o.y = f2b(v.y); o.z = f2b(v.z); o.w = f2b(v.w);
    ((ushort4*)o1)[i] = o;
  }
  for (int i = gid; i < 262144 / 4; i += gs) {
    float4 v = ((const float4*)w2)[i];
    ushort4 o;
    o.x = f2b(v.x); o.y = f2b(v.y); o.z = f2b(v.z); o.w = f2b(v.w);
    ((ushort4*)o2)[i] = o;
  }
}

// one half of x: 4,194,304 floats -> bf16
__global__ __launch_bounds__(256) void cvt_x(const float* __restrict__ x,
                                             unsigned short* __restrict__ xb) {
  const int i = blockIdx.x * 256 + threadIdx.x;  // 0..524287
  const float4 a = ((const float4*)x)[i * 2];
  const float4 b = ((const float4*)x)[i * 2 + 1];
  u16x8 o;
  o[0] = f2b(a.x); o[1] = f2b(a.y); o[2] = f2b(a.z); o[3] = f2b(a.w);
  o[4] = f2b(b.x); o[5] = f2b(b.y); o[6] = f2b(b.z); o[7] = f2b(b.w);
  *(u16x8*)(xb + (size_t)i * 8) = o;
}

// ---------------- MFMA GEMM core: 128x128 tile, K=512, BK=32 ----------------
// A,W bf16 row-major k-contiguous. LDS unpadded [128][32]. 4 waves, each 64x64.
// Staging: global_load_lds 16B/lane; wave wv stages 16-row groups wv*2, wv*2+1.
__device__ __forceinline__ void mfma_512(const unsigned short* __restrict__ A,
                                         const unsigned short* __restrict__ W,
                                         int m0, int n0, int tid,
                                         unsigned short* As, unsigned short* Bs,
                                         f32x4 (&acc)[4][4]) {
  const int lane = tid & 63;
  const int wv = tid >> 6;
  const int wm = wv & 1, wn = wv >> 1;
  const int rr = lane >> 2;        // row within 16-row group
  const int cc = (lane & 3) * 8;   // k elem offset
#pragma unroll
  for (int i = 0; i < 4; ++i)
#pragma unroll
    for (int j = 0; j < 4; ++j) acc[i][j] = f32x4{0.f, 0.f, 0.f, 0.f};

  for (int k0 = 0; k0 < 512; k0 += 32) {
#pragma unroll
    for (int it = 0; it < 2; ++it) {
      const int grp = wv * 2 + it;  // 0..7
      const int row = grp * 16 + rr;
      g2l16(A + (size_t)(m0 + row) * 512 + k0 + cc, As + grp * 512);
      g2l16(W + (size_t)(n0 + row) * 512 + k0 + cc, Bs + grp * 512);
    }
    __syncthreads();
    s16x8 af[4], bf[4];
#pragma unroll
    for (int i = 0; i < 4; ++i) {
      af[i] = *(const s16x8*)&As[(wm * 64 + i * 16 + (lane & 15)) * 32 +
                                 (lane >> 4) * 8];
      bf[i] = *(const s16x8*)&Bs[(wn * 64 + i * 16 + (lane & 15)) * 32 +
                                 (lane >> 4) * 8];
    }
#pragma unroll
    for (int i = 0; i < 4; ++i)
#pragma unroll
      for (int j = 0; j < 4; ++j)
        acc[i][j] = __builtin_amdgcn_mfma_f32_16x16x32_bf16(af[i], bf[j],
                                                            acc[i][j], 0, 0, 0);
    __syncthreads();
  }
}

// ---------------- QKV projection GEMM (half of M) ----------------------------
// grid 768: xcd=id&7 gets row-slabs [xcd*8, xcd*8+8) x 12 col-tiles
__global__ __launch_bounds__(256, 4) void gemm_qkv(
    const unsigned short* __restrict__ A, const unsigned short* __restrict__ W,
    unsigned short* __restrict__ Qb, unsigned short* __restrict__ Kb,
    unsigned short* __restrict__ Vb, int mOutBase) {
  __shared__ unsigned short As[4096], Bs[4096];
  const int tid = threadIdx.x;
  const int id = blockIdx.x;
  const int xcd = id & 7;
  const int j = id >> 3;           // 0..95
  const int by = xcd * 8 + j / 12; // 0..63 (local 128-row slab)
  const int bx = j % 12;
  f32x4 acc[4][4];
  mfma_512(A, W, by * 128, bx * 128, tid, As, Bs, acc);

  const int lane = tid & 63;
  const int wv = tid >> 6;
  const int wm = wv & 1, wn = wv >> 1;
  const int cn = bx * 128 + wn * 64;  // 64-aligned => head/qkv wave-uniform
  unsigned short* dst = (cn < 512) ? Qb : (cn < 1024 ? Kb : Vb);
  const int head = (cn >> 6) & 7;
  const int colb = lane & 15;
#pragma unroll
  for (int mi = 0; mi < 4; ++mi) {
#pragma unroll
    for (int r = 0; r < 4; ++r) {
      const int m = mOutBase + by * 128 + wm * 64 + mi * 16 + (lane >> 4) * 4 + r;
      const int b = m >> 12;
      const int p = m & 4095;
      unsigned short* o =
          dst + ((size_t)(b * kHeads + head) * kN + p) * 64 + colb;
#pragma unroll
      for (int ni = 0; ni < 4; ++ni) o[ni * 16] = f2b(acc[mi][ni][r]);
    }
  }
}

// ---------------- out-projection GEMM ----------------------------------------
// grid 512: xcd=id&7 gets row-slabs [xcd*16, xcd*16+16) x 4 col-tiles
__global__ __launch_bounds__(256, 4) void gemm_out(
    const unsigned short* __restrict__ A, const unsigned short* __restrict__ W,
    const float* __restrict__ bias, float* __restrict__ out) {
  __shared__ unsigned short As[4096], Bs[4096];
  const int tid = threadIdx.x;
  const int id = blockIdx.x;
  const int xcd = id & 7;
  const int j = id >> 3;            // 0..63
  const int by = xcd * 16 + (j >> 2);  // 0..127
  const int bx = j & 3;
  f32x4 acc[4][4];
  mfma_512(A, W, by * 128, bx * 128, tid, As, Bs, acc);

  const int lane = tid & 63;
  const int wv = tid >> 6;
  const int wm = wv & 1, wn = wv >> 1;
  float bvr[4];
#pragma unroll
  for (int ni = 0; ni < 4; ++ni)
    bvr[ni] = bias[bx * 128 + wn * 64 + ni * 16 + (lane & 15)];
#pragma unroll
  for (int mi = 0; mi < 4; ++mi) {
#pragma unroll
    for (int r = 0; r < 4; ++r) {
      const int m = by * 128 + wm * 64 + mi * 16 + (lane >> 4) * 4 + r;
      float* o = out + (size_t)m * 512 + bx * 128 + wn * 64 + (lane & 15);
#pragma unroll
      for (int ni = 0; ni < 4; ++ni) o[ni * 16] = acc[mi][ni][r] + bvr[ni];
    }
  }
}

// ---------------- attention QK + softmax (round-3 proven) --------------------
__global__ __launch_bounds__(256) void attn_qk(
    const unsigned short* __restrict__ Q, const unsigned short* __restrict__ K,
    unsigned short* __restrict__ attnW) {
  __shared__ unsigned short Kh[400 * 72];  // 57.6 KB
  const int tid = threadIdx.x;
  const int bh = blockIdx.y;
  const int tile = blockIdx.x;
  const int ty0 = (tile >> 2) * 16, tx0 = (tile & 3) * 16;
  const size_t base = (size_t)bh * kN;

  for (int i = tid; i < 3200; i += 256) {
    const int r = i >> 3, c = i & 7;
    const int gy = ty0 - 2 + r / 20;
    const int gx = tx0 - 2 + r % 20;
    u16x8 v = {};
    if ((unsigned)gy < 64u && (unsigned)gx < 64u)
      v = *(const u16x8*)(K + (base + gy * 64 + gx) * 64 + c * 8);
    *(u16x8*)&Kh[r * 72 + c * 8] = v;
  }
  __syncthreads();

  const int pyl = tid >> 4, pxl = tid & 15;
  const int p = (ty0 + pyl) * 64 + tx0 + pxl;

  float q[64];
  {
    const unsigned short* qp = Q + (base + p) * 64;
#pragma unroll
    for (int c = 0; c < 8; ++c) {
      const u16x8 v = *(const u16x8*)(qp + c * 8);
#pragma unroll
      for (int jj = 0; jj < 8; ++jj) q[c * 8 + jj] = b2f(v[jj]);
    }
  }

  float dots[25];
  float mx = -1e30f;
#pragma unroll
  for (int fy = 0; fy < 5; ++fy) {
#pragma unroll
    for (int fx = 0; fx < 5; ++fx) {
      const unsigned short* kr = &Kh[((pyl + fy) * 20 + pxl + fx) * 72];
      float d = 0.f;
#pragma unroll
      for (int c = 0; c < 8; ++c) {
        const u16x8 kv = *(const u16x8*)(kr + c * 8);
#pragma unroll
        for (int jj = 0; jj < 8; ++jj) d = fmaf(q[c * 8 + jj], b2f(kv[jj]), d);
      }
      d *= kScale;
      dots[fy * 5 + fx] = d;
      mx = fmaxf(mx, d);
    }
  }
  float sum = 0.f;
#pragma unroll
  for (int f = 0; f < 25; ++f) {
    dots[f] = __expf(dots[f] - mx);
    sum += dots[f];
  }
  const float inv = 1.f / sum;
  unsigned short* ap = attnW + (base + p) * 32;
#pragma unroll
  for (int f = 0; f < 25; ++f) ap[f] = f2b(dots[f] * inv);
}

// ---------------- attention PV (round-3 proven) ------------------------------
__global__ __launch_bounds__(256) void attn_pv(
    const unsigned short* __restrict__ V,
    const unsigned short* __restrict__ attnW,
    unsigned short* __restrict__ AO) {
  __shared__ unsigned short Vh[400 * 72];
  const int tid = threadIdx.x;
  const int bh = blockIdx.y;
  const int tile = blockIdx.x;
  const int ty0 = (tile >> 2) * 16, tx0 = (tile & 3) * 16;
  const size_t base = (size_t)bh * kN;

  for (int i = tid; i < 3200; i += 256) {
    const int r = i >> 3, c = i & 7;
    const int gy = ty0 - 2 + r / 20;
    const int gx = tx0 - 2 + r % 20;
    u16x8 v = {};
    if ((unsigned)gy < 64u && (unsigned)gx < 64u)
      v = *(const u16x8*)(V + (base + gy * 64 + gx) * 64 + c * 8);
    *(u16x8*)&Vh[r * 72 + c * 8] = v;
  }
  __syncthreads();

  const int pyl = tid >> 4, pxl = tid & 15;
  const int p = (ty0 + pyl) * 64 + tx0 + pxl;

  float w[25];
  {
    const unsigned short* ap = attnW + (base + p) * 32;
#pragma unroll
    for (int f = 0; f < 25; ++f) w[f] = b2f(ap[f]);
  }

  float o[64];
#pragma unroll
  for (int jj = 0; jj < 64; ++jj) o[jj] = 0.f;

#pragma unroll
  for (int fy = 0; fy < 5; ++fy) {
#pragma unroll
    for (int fx = 0; fx < 5; ++fx) {
      const unsigned short* vr = &Vh[((pyl + fy) * 20 + pxl + fx) * 72];
      const float wf = w[fy * 5 + fx];
#pragma unroll
      for (int c = 0; c < 8; ++c) {
        const u16x8 vv = *(const u16x8*)(vr + c * 8);
#pragma unroll
        for (int jj = 0; jj < 8; ++jj)
          o[c * 8 + jj] = fmaf(wf, b2f(vv[jj]), o[c * 8 + jj]);
      }
    }
  }

  const int b = bh >> 3, h = bh & 7;
  unsigned short* op = AO + ((size_t)(b * kN + p)) * 512 + h * 64;
#pragma unroll
  for (int c = 0; c < 8; ++c) {
    u16x8 pk;
#pragma unroll
    for (int jj = 0; jj < 8; ++jj) pk[jj] = f2b(o[c * 8 + jj]);
    *(u16x8*)(op + c * 8) = pk;
  }
}

}  // namespace

extern "C" void kernel_launch(void* const* d_in, const int* in_sizes, int n_in,
                              void* d_out, int out_size, void* d_ws,
                              size_t ws_size, hipStream_t stream) {
  (void)in_sizes; (void)n_in; (void)out_size; (void)ws_size;
  const float* x = (const float*)d_in[0];      // [4,4096,512]
  const float* w_qkv = (const float*)d_in[1];  // [1536,512]
  const float* w_out = (const float*)d_in[2];  // [512,512]
  const float* b_out = (const float*)d_in[3];  // [512]
  float* out = (float*)d_out;                  // [4,4096,512] fp32

  unsigned short* ws0 = (unsigned short*)d_ws;
  unsigned short* wqkvb = ws0;                  //   786,432
  unsigned short* woutb = ws0 + 786432;         //   262,144
  unsigned short* xbh   = ws0 + 1048576;        // 4,194,304 (half of x; attnW later)
  unsigned short* Qb    = ws0 + 5242880;        // 8,388,608
  unsigned short* Kb    = ws0 + 13631488;       // 8,388,608
  unsigned short* Vb    = ws0 + 22020096;       // 8,388,608 -> end 30,408,704 (60.8 MB)
  unsigned short* attnW = xbh;                  // xbh dead after gemm_qkv half 1
  unsigned short* AO    = Qb;                   // Q dead after attn_qk

  cvt_w<<<512, 256, 0, stream>>>(w_qkv, w_out, wqkvb, woutb);
  cvt_x<<<2048, 256, 0, stream>>>(x, xbh);  // rows 0..8191
  gemm_qkv<<<768, 256, 0, stream>>>(xbh, wqkvb, Qb, Kb, Vb, 0);
  cvt_x<<<2048, 256, 0, stream>>>(x + 4194304, xbh);  // rows 8192..16383
  gemm_qkv<<<768, 256, 0, stream>>>(xbh, wqkvb, Qb, Kb, Vb, 8192);
  attn_qk<<<dim3(16, 32), 256, 0, stream>>>(Qb, Kb, attnW);
  attn_pv<<<dim3(16, 32), 256, 0, stream>>>(Vb, attnW, AO);
  gemm_out<<<512, 256, 0, stream>>>(AO, woutb, b_out, out);
}